// Round 2
// baseline (199.700 us; speedup 1.0000x reference)
//
#include <hip/hip_runtime.h>

// Problem constants (from reference): B,R,C,H,W = 4,2,19,256,512
constexpr int B = 4, R = 2, C = 19, H = 256, W = 512;
constexpr int HW = H * W;
constexpr int NBLK = (B * HW) / 256;   // 2048 pixel-blocks (each = half a row)
constexpr int NXCD = 8;
constexpr int BLK_PER_XCD = NBLK / NXCD;  // 256

__global__ __launch_bounds__(256) void mc_warp_kernel(
    const float* __restrict__ pred,   // [B,R,C,H,W]
    const float* __restrict__ mv,     // [B,R,2,H,W] quarter-pel
    const float* __restrict__ wgt,    // [B,R,1,H,W]
    float* __restrict__ out)          // [B,C,H,W]
{
    // XCD band swizzle: consecutive hardware XCD (blockIdx.x % 8) gets a
    // contiguous band of (b,y) rows so pred tap rows stay in one XCD's L2.
    int xcd  = blockIdx.x & (NXCD - 1);
    int slot = blockIdx.x >> 3;
    int vblk = xcd * BLK_PER_XCD + slot;          // band-contiguous virtual block
    int idx  = vblk * 256 + threadIdx.x;          // b*HW + y*W + x

    int x = idx & (W - 1);
    int y = (idx >> 9) & (H - 1);     // W = 512 = 2^9
    int b = idx / HW;
    int pix = y * W + x;

    int   lin[R][4];
    float wt[R][4];

    #pragma unroll
    for (int r = 0; r < R; ++r) {
        const float* mvb = mv + ((size_t)(b * R + r) * 2) * HW + pix;
        float mx = mvb[0]  * 0.25f;   // quarter-pel -> pixel
        float my = mvb[HW] * 0.25f;
        float gx = (float)x + mx;
        float gy = (float)y + my;
        float fx0 = floorf(gx), fy0 = floorf(gy);
        float wx1 = gx - fx0, wx0 = 1.0f - wx1;
        float wy1 = gy - fy0, wy0 = 1.0f - wy1;
        float wr = wgt[(size_t)(b * R + r) * HW + pix];

        int ix0 = (int)fx0, iy0 = (int)fy0;
        int ix1 = ix0 + 1,  iy1 = iy0 + 1;
        bool vx0 = (ix0 >= 0) && (ix0 <= W - 1);
        bool vx1 = (ix1 >= 0) && (ix1 <= W - 1);
        bool vy0 = (iy0 >= 0) && (iy0 <= H - 1);
        bool vy1 = (iy1 >= 0) && (iy1 <= H - 1);
        int cx0 = min(max(ix0, 0), W - 1), cx1 = min(max(ix1, 0), W - 1);
        int cy0 = min(max(iy0, 0), H - 1), cy1 = min(max(iy1, 0), H - 1);

        lin[r][0] = cy0 * W + cx0;  wt[r][0] = wy0 * wx0 * ((vy0 && vx0) ? wr : 0.0f);
        lin[r][1] = cy0 * W + cx1;  wt[r][1] = wy0 * wx1 * ((vy0 && vx1) ? wr : 0.0f);
        lin[r][2] = cy1 * W + cx0;  wt[r][2] = wy1 * wx0 * ((vy1 && vx0) ? wr : 0.0f);
        lin[r][3] = cy1 * W + cx1;  wt[r][3] = wy1 * wx1 * ((vy1 && vx1) ? wr : 0.0f);
    }

    const float* p0 = pred + (size_t)(b * R + 0) * C * HW;
    const float* p1 = pred + (size_t)(b * R + 1) * C * HW;
    float* ob = out + (size_t)b * C * HW + pix;

    // Split channels across gridDim.y (2 halves: 10 + 9) for 2x wave count.
    int cbeg = (blockIdx.y == 0) ? 0 : 10;
    int cend = (blockIdx.y == 0) ? 10 : 19;

    #pragma unroll 2
    for (int c = cbeg; c < cend; ++c) {
        const float* pc0 = p0 + (size_t)c * HW;
        const float* pc1 = p1 + (size_t)c * HW;
        float v[8];
        #pragma unroll
        for (int t = 0; t < 4; ++t) v[t]     = pc0[lin[0][t]];
        #pragma unroll
        for (int t = 0; t < 4; ++t) v[4 + t] = pc1[lin[1][t]];
        float acc = 0.0f;
        #pragma unroll
        for (int t = 0; t < 4; ++t) acc += wt[0][t] * v[t];
        #pragma unroll
        for (int t = 0; t < 4; ++t) acc += wt[1][t] * v[4 + t];
        ob[(size_t)c * HW] = acc;
    }
}

extern "C" void kernel_launch(void* const* d_in, const int* in_sizes, int n_in,
                              void* d_out, int out_size, void* d_ws, size_t ws_size,
                              hipStream_t stream) {
    const float* pred = (const float*)d_in[0];   // [B,R,C,H,W] fp32
    const float* mv   = (const float*)d_in[1];   // [B,R,2,H,W] fp32
    const float* wgt  = (const float*)d_in[2];   // [B,R,1,H,W] fp32
    float* out = (float*)d_out;                  // [B,C,H,W] fp32

    dim3 grid(NBLK, 2);                          // 2048 pixel-blocks x 2 channel halves
    mc_warp_kernel<<<grid, dim3(256), 0, stream>>>(pred, mv, wgt, out);
}

// Round 3
// 194.064 us; speedup vs baseline: 1.0290x; 1.0290x over previous
//
#include <hip/hip_runtime.h>

// Problem constants (from reference): B,R,C,H,W = 4,2,19,256,512
constexpr int B = 4, R = 2, C = 19, H = 256, W = 512;
constexpr int HW = H * W;
constexpr int NBLK = (B * HW) / 256;      // 2048 pixel-blocks (each = half a row)
constexpr int NXCD = 8;
constexpr int BLK_PER_XCD = NBLK / NXCD;  // 256

__global__ __launch_bounds__(256, 8) void mc_warp_kernel(
    const float* __restrict__ pred,   // [B,R,C,H,W]
    const float* __restrict__ mv,     // [B,R,2,H,W] quarter-pel
    const float* __restrict__ wgt,    // [B,R,1,H,W]
    float* __restrict__ out)          // [B,C,H,W]
{
    // XCD band swizzle: blockIdx.x % 8 is (approximately) the hardware XCD;
    // give each XCD a contiguous band of (b,y) rows for L2 tap locality.
    int xcd  = blockIdx.x & (NXCD - 1);
    int slot = blockIdx.x >> 3;
    int vblk = xcd * BLK_PER_XCD + slot;
    int idx  = vblk * 256 + threadIdx.x;          // b*HW + y*W + x

    int x = idx & (W - 1);
    int y = (idx >> 9) & (H - 1);                 // W = 512 = 2^9
    int b = idx / HW;
    int pix = y * W + x;

    // Per ref: two pair-gather base offsets (row y0, row y1) + 4 pair weights.
    // The 2x2 bilinear stencil's x-taps are adjacent -> one dwordx2 per row.
    int   addr[R][2];
    float pw[R][4];   // w(row0,elem0), w(row0,elem1), w(row1,elem0), w(row1,elem1)

    #pragma unroll
    for (int r = 0; r < R; ++r) {
        const float* mvb = mv + ((size_t)(b * R + r) * 2) * HW + pix;
        float mx = mvb[0]  * 0.25f;   // quarter-pel -> pixel
        float my = mvb[HW] * 0.25f;
        float gx = (float)x + mx;
        float gy = (float)y + my;
        float fx0 = floorf(gx), fy0 = floorf(gy);
        float wx1 = gx - fx0, wx0 = 1.0f - wx1;
        float wy1 = gy - fy0, wy0 = 1.0f - wy1;
        float wr = wgt[(size_t)(b * R + r) * HW + pix];

        int ix0 = (int)fx0, iy0 = (int)fy0;
        int ix1 = ix0 + 1,  iy1 = iy0 + 1;

        // Shift the pair base into [0, W-2]; route wx0/wx1 to whichever pair
        // element its tap landed on (0 if the tap is out of range: zeros pad).
        int base = min(max(ix0, 0), W - 2);
        float wA = (ix0 == base)     ? wx0 : ((ix1 == base)     ? wx1 : 0.0f);
        float wB = (ix1 == base + 1) ? wx1 : ((ix0 == base + 1) ? wx0 : 0.0f);

        float wy0v = ((iy0 >= 0) && (iy0 < H)) ? wy0 * wr : 0.0f;
        float wy1v = ((iy1 >= 0) && (iy1 < H)) ? wy1 * wr : 0.0f;
        int cy0 = min(max(iy0, 0), H - 1);
        int cy1 = min(max(iy1, 0), H - 1);

        addr[r][0] = cy0 * W + base;
        addr[r][1] = cy1 * W + base;
        pw[r][0] = wy0v * wA;
        pw[r][1] = wy0v * wB;
        pw[r][2] = wy1v * wA;
        pw[r][3] = wy1v * wB;
    }

    const float* p0 = pred + (size_t)(b * R + 0) * C * HW;
    const float* p1 = pred + (size_t)(b * R + 1) * C * HW;
    float* ob = out + (size_t)b * C * HW + pix;

    #pragma unroll 2
    for (int c = 0; c < C; ++c) {
        const float* pc0 = p0 + (size_t)c * HW;
        const float* pc1 = p1 + (size_t)c * HW;
        // 4 pair-gathers (8B each, possibly 4B-aligned — gfx950 handles it).
        float2 v00, v01, v10, v11;
        __builtin_memcpy(&v00, pc0 + addr[0][0], 8);
        __builtin_memcpy(&v01, pc0 + addr[0][1], 8);
        __builtin_memcpy(&v10, pc1 + addr[1][0], 8);
        __builtin_memcpy(&v11, pc1 + addr[1][1], 8);
        float acc = pw[0][0] * v00.x + pw[0][1] * v00.y
                  + pw[0][2] * v01.x + pw[0][3] * v01.y
                  + pw[1][0] * v10.x + pw[1][1] * v10.y
                  + pw[1][2] * v11.x + pw[1][3] * v11.y;
        ob[(size_t)c * HW] = acc;
    }
}

extern "C" void kernel_launch(void* const* d_in, const int* in_sizes, int n_in,
                              void* d_out, int out_size, void* d_ws, size_t ws_size,
                              hipStream_t stream) {
    const float* pred = (const float*)d_in[0];   // [B,R,C,H,W] fp32
    const float* mv   = (const float*)d_in[1];   // [B,R,2,H,W] fp32
    const float* wgt  = (const float*)d_in[2];   // [B,R,1,H,W] fp32
    float* out = (float*)d_out;                  // [B,C,H,W] fp32

    mc_warp_kernel<<<NBLK, 256, 0, stream>>>(pred, mv, wgt, out);
}

// Round 4
// 175.253 us; speedup vs baseline: 1.1395x; 1.1073x over previous
//
#include <hip/hip_runtime.h>

// Problem constants (from reference): B,R,C,H,W = 4,2,19,256,512
constexpr int B = 4, R = 2, C = 19, H = 256, W = 512;
constexpr int HW = H * W;

// Output tile per block: 64 x 16 px; 256 threads, each thread = 4 consecutive x.
constexpr int BX = 64, BY = 16;
constexpr int NBX = W / BX;              // 8
constexpr int NBY = H / BY;              // 16
constexpr int NBLOCKS = B * NBX * NBY;   // 512

// Pred tile staged in LDS per (channel, ref): halo 12 px (6 sigma of mv).
constexpr int TW = 92;                   // 64 + 2*12 + pair/floor slack, 4-aligned base
constexpr int TH = 42;                   // 16 + 2*12 + slack
constexpr int TILE_N = TW * TH;          // 3864 floats = 15.46 KB
constexpr int TILE_V4 = TILE_N / 4;      // 966 float4s (TW/4 = 23 per row)

__global__ __launch_bounds__(256, 4) void mc_warp_kernel(
    const float* __restrict__ pred,   // [B,R,C,H,W]
    const float* __restrict__ mv,     // [B,R,2,H,W] quarter-pel
    const float* __restrict__ wgt,    // [B,R,1,H,W]
    float* __restrict__ out)          // [B,C,H,W]
{
    __shared__ float tile0[TILE_N];
    __shared__ float tile1[TILE_N];

    int t = threadIdx.x;
    // XCD band swizzle: each XCD owns a contiguous (b, y-band); y-adjacent
    // tiles (sharing halo rows) land on the same XCD's L2.
    int xcd  = blockIdx.x & 7;
    int slot = blockIdx.x >> 3;
    int vblk = xcd * (NBLOCKS / 8) + slot;
    int bx   = vblk & (NBX - 1);
    int rest = vblk >> 3;
    int by   = rest & (NBY - 1);
    int b    = rest >> 4;
    int x0 = bx * BX, y0 = by * BY;
    int tx = t & 15, ty = t >> 4;
    int y  = y0 + ty;
    int xb = x0 + tx * 4;                 // first of this thread's 4 px

    // Tile origin, clamped fully inside the image (staging needs no clamps).
    int rowbase = min(max(y0 - 12, 0), H - TH);
    int colbase = min(max(x0 - 12, 0), W - TW);   // stays 4-aligned

    // Per-(ref, px) tap state: two row-pair offsets + 4 pair weights.
    int   off0[R][4], off1[R][4];
    int   offL0[R][4], offL1[R][4], offG0[R][4], offG1[R][4];
    float wq[R][4][4];
    int flag = 0;

    #pragma unroll
    for (int r = 0; r < R; ++r) {
        const float* mvp = mv + (size_t)((b * R + r) * 2) * HW + (size_t)y * W + xb;
        float4 mx4 = *(const float4*)(mvp);
        float4 my4 = *(const float4*)(mvp + HW);
        float4 wr4 = *(const float4*)(wgt + (size_t)(b * R + r) * HW + (size_t)y * W + xb);
        float mxs[4] = {mx4.x, mx4.y, mx4.z, mx4.w};
        float mys[4] = {my4.x, my4.y, my4.z, my4.w};
        float wrs[4] = {wr4.x, wr4.y, wr4.z, wr4.w};
        #pragma unroll
        for (int p = 0; p < 4; ++p) {
            int x = xb + p;
            float gx = (float)x + mxs[p] * 0.25f;   // quarter-pel -> pixel
            float gy = (float)y + mys[p] * 0.25f;
            float fx0 = floorf(gx), fy0 = floorf(gy);
            float wx1 = gx - fx0, wx0 = 1.0f - wx1;
            float wy1 = gy - fy0, wy0 = 1.0f - wy1;
            int ix0 = (int)fx0, iy0 = (int)fy0;
            int ix1 = ix0 + 1,  iy1 = iy0 + 1;

            // x pair: shift base into [0, W-2], route wx0/wx1 per element.
            int base = min(max(ix0, 0), W - 2);
            float wA = (ix0 == base)     ? wx0 : ((ix1 == base)     ? wx1 : 0.0f);
            float wB = (ix1 == base + 1) ? wx1 : ((ix0 == base + 1) ? wx0 : 0.0f);
            float wr = wrs[p];
            float wy0v = ((iy0 >= 0) && (iy0 < H)) ? wy0 * wr : 0.0f;
            float wy1v = ((iy1 >= 0) && (iy1 < H)) ? wy1 * wr : 0.0f;
            int cy0 = min(max(iy0, 0), H - 1);
            int cy1 = min(max(iy1, 0), H - 1);

            int l0 = base - colbase;
            int r0 = cy0 - rowbase, r1 = cy1 - rowbase;
            bool anyx = (wA != 0.0f) || (wB != 0.0f);
            bool anyy = (wy0v != 0.0f) || (wy1v != 0.0f);
            bool cb  = (l0 < 0 || l0 > TW - 2) && anyx && anyy;
            bool rb0 = (r0 < 0 || r0 > TH - 1) && (wy0v != 0.0f) && anyx;
            bool rb1 = (r1 < 0 || r1 > TH - 1) && (wy1v != 0.0f) && anyx;
            flag |= (int)(cb || rb0 || rb1);
            l0 = min(max(l0, 0), TW - 2);
            r0 = min(max(r0, 0), TH - 1);
            r1 = min(max(r1, 0), TH - 1);

            offL0[r][p] = r0 * TW + l0;
            offL1[r][p] = r1 * TW + l0;
            offG0[r][p] = cy0 * W + base;
            offG1[r][p] = cy1 * W + base;
            wq[r][p][0] = wy0v * wA;
            wq[r][p][1] = wy0v * wB;
            wq[r][p][2] = wy1v * wA;
            wq[r][p][3] = wy1v * wB;
        }
    }

    // Block-uniform fallback decision: if ANY tap escaped the halo (|mv|>~12px,
    // ~6 sigma; essentially never), the whole block uses global gathers.
    int fbB = __syncthreads_or(flag);
    #pragma unroll
    for (int r = 0; r < R; ++r)
        #pragma unroll
        for (int p = 0; p < 4; ++p) {
            off0[r][p] = fbB ? offG0[r][p] : offL0[r][p];
            off1[r][p] = fbB ? offG1[r][p] : offL1[r][p];
        }

    const float* pl0 = pred + (size_t)(b * R + 0) * C * HW;
    const float* pl1 = pred + (size_t)(b * R + 1) * C * HW;
    const float* st0 = pl0 + (size_t)rowbase * W + colbase;
    const float* st1 = pl1 + (size_t)rowbase * W + colbase;
    float* ob = out + (size_t)b * C * HW + (size_t)y * W + xb;

    for (int c = 0; c < C; ++c) {
        __syncthreads();   // previous channel's LDS reads done before restage
        if (!fbB) {
            const float* s0 = st0 + (size_t)c * HW;
            const float* s1 = st1 + (size_t)c * HW;
            #pragma unroll
            for (int i = 0; i < 4; ++i) {
                int idx = t + i * 256;
                if (idx < TILE_V4) {
                    int row = idx / 23;              // 23 float4s per tile row
                    int c4  = (idx - row * 23) * 4;
                    float4 v0 = *(const float4*)(s0 + row * W + c4);
                    float4 v1 = *(const float4*)(s1 + row * W + c4);
                    *(float4*)&tile0[row * TW + c4] = v0;
                    *(float4*)&tile1[row * TW + c4] = v1;
                }
            }
        }
        __syncthreads();

        float res[4];
        if (!fbB) {
            #pragma unroll
            for (int p = 0; p < 4; ++p) {
                float a00 = tile0[off0[0][p]], a01 = tile0[off0[0][p] + 1];
                float a10 = tile0[off1[0][p]], a11 = tile0[off1[0][p] + 1];
                float b00 = tile1[off0[1][p]], b01 = tile1[off0[1][p] + 1];
                float b10 = tile1[off1[1][p]], b11 = tile1[off1[1][p] + 1];
                res[p] = wq[0][p][0] * a00 + wq[0][p][1] * a01
                       + wq[0][p][2] * a10 + wq[0][p][3] * a11
                       + wq[1][p][0] * b00 + wq[1][p][1] * b01
                       + wq[1][p][2] * b10 + wq[1][p][3] * b11;
            }
        } else {
            const float* pc0 = pl0 + (size_t)c * HW;
            const float* pc1 = pl1 + (size_t)c * HW;
            #pragma unroll
            for (int p = 0; p < 4; ++p) {
                float a00 = pc0[off0[0][p]], a01 = pc0[off0[0][p] + 1];
                float a10 = pc0[off1[0][p]], a11 = pc0[off1[0][p] + 1];
                float b00 = pc1[off0[1][p]], b01 = pc1[off0[1][p] + 1];
                float b10 = pc1[off1[1][p]], b11 = pc1[off1[1][p] + 1];
                res[p] = wq[0][p][0] * a00 + wq[0][p][1] * a01
                       + wq[0][p][2] * a10 + wq[0][p][3] * a11
                       + wq[1][p][0] * b00 + wq[1][p][1] * b01
                       + wq[1][p][2] * b10 + wq[1][p][3] * b11;
            }
        }
        *(float4*)(ob + (size_t)c * HW) = make_float4(res[0], res[1], res[2], res[3]);
    }
}

extern "C" void kernel_launch(void* const* d_in, const int* in_sizes, int n_in,
                              void* d_out, int out_size, void* d_ws, size_t ws_size,
                              hipStream_t stream) {
    const float* pred = (const float*)d_in[0];   // [B,R,C,H,W] fp32
    const float* mv   = (const float*)d_in[1];   // [B,R,2,H,W] fp32
    const float* wgt  = (const float*)d_in[2];   // [B,R,1,H,W] fp32
    float* out = (float*)d_out;                  // [B,C,H,W] fp32

    mc_warp_kernel<<<NBLOCKS, 256, 0, stream>>>(pred, mv, wgt, out);
}